// Round 10
// baseline (267.124 us; speedup 1.0000x reference)
//
#include <hip/hip_runtime.h>
#include <hip/hip_fp16.h>
#include <math.h>

// GAT layer: N=50000, E=800000, IN=256, H=4, C=32.
// R10: dispatch-count reduction (10 -> 7) + wD elimination.
//  - k_prep     : fused hist-zero + W transpose/bf16
//  - k_gemm_mfma: R9 barrier-free-K 32x32x16 MFMA GEMM (unchanged)
//  - k_hist/scanC/scatterC : R8 bucketed CSR build (unchanged)
//  - k_rebin    : node-level CSR build; S-side blocks ALSO compute rdenom
//                 via LDS float atomics (k_denom fused in)
//  - k_agg      : dst-CSR gather; per-edge weights computed in-wave
//                 (1 expf/edge, broadcast via __shfl) — k_wedge + wD gone.

#define NH 4
#define CH 32
#define HC 128
#define IND 256
#define NEG_SLOPE 0.2f
#define CSH 8           // coarse bucket = 256 nodes
#define NCB_MAX 256
#define CHUNK 4096

typedef __attribute__((ext_vector_type(8))) short bf16x8;
typedef __attribute__((ext_vector_type(16))) float f32x16;

__device__ __forceinline__ unsigned short f2bf(float f) {
    unsigned int u = __float_as_uint(f);
    unsigned int r = (u + 0x7FFFu + ((u >> 16) & 1u)) >> 16;   // RNE
    return (unsigned short)r;
}
__device__ __forceinline__ float bf2f(unsigned short s) {
    return __uint_as_float(((unsigned int)s) << 16);
}

// fused: WT_bf[c][k] = bf16(W[k][c]) ; block 0 zeroes coarse hists.
__global__ __launch_bounds__(256) void k_prep(const float* __restrict__ W,
                                              unsigned short* __restrict__ WT_bf,
                                              int* __restrict__ histS,
                                              int* __restrict__ histD, int ncb) {
    int t = blockIdx.x * 256 + threadIdx.x;
    if (t < IND * HC) {
        int c = t >> 8;
        int k = t & 255;
        WT_bf[t] = f2bf(W[k * HC + c]);
    }
    if (blockIdx.x == 0 && threadIdx.x < ncb) {
        histS[threadIdx.x] = 0;
        histD[threadIdx.x] = 0;
    }
}

// h_bf = bf16(x @ W) via 32x32x16 MFMA, barrier-free K-loop (R9).
__global__ __launch_bounds__(256) void k_gemm_mfma(const float* __restrict__ x,
                                                   const unsigned short* __restrict__ WT_bf,
                                                   const float* __restrict__ att,
                                                   unsigned short* __restrict__ h_bf,
                                                   float* __restrict__ al,
                                                   float* __restrict__ ar, int N) {
    __shared__ float cs[128 * 129];                    // 66048 B
    unsigned short* wsT = (unsigned short*)cs;         // [128][258]

    const int tid  = threadIdx.x;
    const int row0 = blockIdx.x * 128;
    const int wave = tid >> 6;
    const int lane = tid & 63;
    const int n32  = lane & 31;
    const int half = lane >> 5;

    {
        int c  = tid >> 1;
        int kh = (tid & 1) * 128;
        const unsigned short* src = WT_bf + c * IND + kh;
        unsigned short* dst = wsT + c * 258 + kh;
#pragma unroll
        for (int j = 0; j < 128; j += 8)
            *(int4*)(dst + j) = *(const int4*)(src + j);
    }
    __syncthreads();

    const int row    = row0 + wave * 32 + n32;
    const bool valid = row < N;
    const float* xrow = x + (size_t)row * IND + half * 8;

    f32x16 acc[4];
#pragma unroll
    for (int t = 0; t < 4; t++)
#pragma unroll
        for (int r = 0; r < 16; r++) acc[t][r] = 0.0f;

#pragma unroll 4
    for (int s = 0; s < 16; s++) {
        float4 v0 = make_float4(0.f, 0.f, 0.f, 0.f);
        float4 v1 = v0;
        if (valid) {
            v0 = *(const float4*)(xrow + s * 16);
            v1 = *(const float4*)(xrow + s * 16 + 4);
        }
        bf16x8 a;
        a[0] = (short)f2bf(v0.x); a[1] = (short)f2bf(v0.y);
        a[2] = (short)f2bf(v0.z); a[3] = (short)f2bf(v0.w);
        a[4] = (short)f2bf(v1.x); a[5] = (short)f2bf(v1.y);
        a[6] = (short)f2bf(v1.z); a[7] = (short)f2bf(v1.w);
#pragma unroll
        for (int t = 0; t < 4; t++) {
            bf16x8 b = *(const bf16x8*)(wsT + (t * 32 + n32) * 258 + s * 16 + half * 8);
            acc[t] = __builtin_amdgcn_mfma_f32_32x32x16_bf16(a, b, acc[t], 0, 0, 0);
        }
    }
    __syncthreads();   // wsT dead; cs aliases it

#pragma unroll
    for (int t = 0; t < 4; t++)
#pragma unroll
        for (int r = 0; r < 16; r++) {
            int rl = wave * 32 + (r & 3) + 8 * (r >> 2) + 4 * half;
            cs[rl * 129 + t * 32 + n32] = acc[t][r];
        }
    __syncthreads();

    const int rl   = tid >> 1;
    const int chf  = tid & 1;
    const int orow = row0 + rl;
    if (orow < N) {
        const float* cr = cs + rl * 129 + chf * 64;
        unsigned short* hp = h_bf + (size_t)orow * HC + chf * 64;
#pragma unroll
        for (int c = 0; c < 64; c += 8) {
            ushort4 o0, o1;
            o0.x = f2bf(cr[c]);     o0.y = f2bf(cr[c + 1]);
            o0.z = f2bf(cr[c + 2]); o0.w = f2bf(cr[c + 3]);
            o1.x = f2bf(cr[c + 4]); o1.y = f2bf(cr[c + 5]);
            o1.z = f2bf(cr[c + 6]); o1.w = f2bf(cr[c + 7]);
            *(ushort4*)(hp + c) = o0;
            *(ushort4*)(hp + c + 4) = o1;
        }
        const int h0 = 2 * chf, h1 = 2 * chf + 1;
        const float* w0 = att + h0 * (2 * CH);
        const float* w1 = att + h1 * (2 * CH);
        float sl0 = 0.f, sr0 = 0.f, sl1 = 0.f, sr1 = 0.f;
#pragma unroll
        for (int c = 0; c < CH; c++) {
            float v0 = cr[c];
            float v1 = cr[CH + c];
            sl0 += v0 * w0[c];  sr0 += v0 * w0[CH + c];
            sl1 += v1 * w1[c];  sr1 += v1 * w1[CH + c];
        }
        al[orow * NH + h0] = sl0;  al[orow * NH + h1] = sl1;
        ar[orow * NH + h0] = sr0;  ar[orow * NH + h1] = sr1;
    }
}

// coarse histograms, LDS-staged.
__global__ __launch_bounds__(256) void k_hist(const int* __restrict__ ei,
                                              int* __restrict__ histS,
                                              int* __restrict__ histD,
                                              int E, int NE, int ncb) {
    __shared__ int hs[NCB_MAX], hd[NCB_MAX];
    hs[threadIdx.x] = 0; hd[threadIdx.x] = 0;
    __syncthreads();
    for (int t = blockIdx.x * 256 + threadIdx.x; t < NE; t += gridDim.x * 256) {
        int src, dst;
        if (t < E) { src = ei[t]; dst = ei[E + t]; }
        else       { src = dst = t - E; }
        atomicAdd(&hs[src >> CSH], 1);
        atomicAdd(&hd[dst >> CSH], 1);
    }
    __syncthreads();
    int i = threadIdx.x;
    if (i < ncb) {
        if (hs[i]) atomicAdd(&histS[i], hs[i]);
        if (hd[i]) atomicAdd(&histD[i], hd[i]);
    }
}

// one block: parallel exclusive scan over ncb buckets, both sides.
__global__ __launch_bounds__(256) void k_scanC(const int* __restrict__ histS,
                                               const int* __restrict__ histD,
                                               int* __restrict__ baseS,
                                               int* __restrict__ baseD,
                                               int* __restrict__ curS,
                                               int* __restrict__ curD,
                                               int* __restrict__ rowptrS,
                                               int* __restrict__ rowptrD,
                                               int ncb, int NE, int N) {
    __shared__ int sc[256];
    int tid = threadIdx.x;
    int v = (tid < ncb) ? histS[tid] : 0;
    sc[tid] = v;
    __syncthreads();
    for (int o = 1; o < 256; o <<= 1) {
        int t = (tid >= o) ? sc[tid - o] : 0;
        __syncthreads();
        sc[tid] += t;
        __syncthreads();
    }
    if (tid < ncb) { baseS[tid] = sc[tid] - v; curS[tid] = sc[tid] - v; }
    if (tid == 0) { baseS[ncb] = sc[255]; rowptrS[N] = NE; }
    __syncthreads();
    v = (tid < ncb) ? histD[tid] : 0;
    sc[tid] = v;
    __syncthreads();
    for (int o = 1; o < 256; o <<= 1) {
        int t = (tid >= o) ? sc[tid - o] : 0;
        __syncthreads();
        sc[tid] += t;
        __syncthreads();
    }
    if (tid < ncb) { baseD[tid] = sc[tid] - v; curD[tid] = sc[tid] - v; }
    if (tid == 0) { baseD[ncb] = sc[255]; rowptrD[N] = NE; }
}

// chunked scatter into coarse streams, LDS-binned (full-line appends).
__global__ __launch_bounds__(256) void k_scatterC(const int* __restrict__ ei,
                                                  int* __restrict__ gcurS,
                                                  int* __restrict__ gcurD,
                                                  unsigned int* __restrict__ recS,
                                                  unsigned int* __restrict__ recD,
                                                  int E, int NE, int ncb) {
    __shared__ unsigned int srt[CHUNK];          // 16 KB
    __shared__ int cnt[NCB_MAX], off[NCB_MAX], cur[NCB_MAX], gpos[NCB_MAX], sc[256];
    const int tid = threadIdx.x;
    const int t0  = blockIdx.x * CHUNK;
    const int m   = min(CHUNK, NE - t0);

    unsigned int myrec[CHUNK / 256];
    int nmy = 0;
    for (int i = tid; i < m; i += 256) {
        int t = t0 + i;
        int src, dst;
        if (t < E) { src = ei[t]; dst = ei[E + t]; }
        else       { src = dst = t - E; }
        myrec[nmy++] = (unsigned int)src | ((unsigned int)dst << 16);
    }

    for (int side = 0; side < 2; side++) {       // 0 = S (by src), 1 = D (by dst)
        cnt[tid] = 0;
        __syncthreads();
        int mybkt[CHUNK / 256];
        for (int k = 0; k < nmy; k++) {
            unsigned int r = myrec[k];
            int node = side ? (int)(r >> 16) : (int)(r & 0xFFFFu);
            mybkt[k] = node >> CSH;
            atomicAdd(&cnt[mybkt[k]], 1);
        }
        __syncthreads();
        int v = cnt[tid];
        sc[tid] = v;
        __syncthreads();
        for (int o = 1; o < 256; o <<= 1) {
            int t = (tid >= o) ? sc[tid - o] : 0;
            __syncthreads();
            sc[tid] += t;
            __syncthreads();
        }
        off[tid] = sc[tid] - v;
        cur[tid] = sc[tid] - v;
        __syncthreads();
        for (int k = 0; k < nmy; k++) {
            int p = atomicAdd(&cur[mybkt[k]], 1);
            srt[p] = myrec[k];
        }
        __syncthreads();
        int* gcur = side ? gcurD : gcurS;
        if (tid < ncb) {
            int c = cnt[tid];
            gpos[tid] = c ? atomicAdd(&gcur[tid], c) : 0;
        }
        __syncthreads();
        unsigned int* recX = side ? recD : recS;
        for (int i = tid; i < m; i += 256) {
            unsigned int r = srt[i];
            int node = side ? (int)(r >> 16) : (int)(r & 0xFFFFu);
            int cb = node >> CSH;
            recX[gpos[cb] + (i - off[cb])] = r;
        }
        __syncthreads();
    }
}

// block per (side, coarse bucket): node-level CSR inside private region.
// S-side blocks additionally compute rdenom (fused k_denom) via LDS f32 adds.
__global__ __launch_bounds__(256) void k_rebin(const unsigned int* __restrict__ recS,
                                               const unsigned int* __restrict__ recD,
                                               const int* __restrict__ baseS,
                                               const int* __restrict__ baseD,
                                               unsigned short* __restrict__ adjS,
                                               unsigned short* __restrict__ adjD,
                                               int* __restrict__ rowptrS,
                                               int* __restrict__ rowptrD,
                                               const float* __restrict__ al,
                                               const float* __restrict__ ar,
                                               float* __restrict__ rdenom,
                                               int ncb, int N) {
    __shared__ int cnt[256], cur[256], sc[256];
    __shared__ float den[256 * NH];                 // 4 KB
    const int tid  = threadIdx.x;
    const int side = (blockIdx.x >= ncb) ? 1 : 0;
    const int cb   = side ? blockIdx.x - ncb : blockIdx.x;
    const unsigned int* rec = side ? recD : recS;
    const int* base = side ? baseD : baseS;
    const int b0 = base[cb], b1 = base[cb + 1];
    const int tot_rec = b1 - b0;

    cnt[tid] = 0;
    if (side == 0) {
#pragma unroll
        for (int h = 0; h < NH; h++) den[tid * NH + h] = 0.f;
    }
    __syncthreads();
    for (int i = tid; i < tot_rec; i += 256) {
        unsigned int r = rec[b0 + i];
        int node = side ? (int)(r >> 16) : (int)(r & 0xFFFFu);
        atomicAdd(&cnt[node & 255], 1);
    }
    __syncthreads();
    int v = cnt[tid];
    sc[tid] = v;
    __syncthreads();
    for (int o = 1; o < 256; o <<= 1) {
        int t = (tid >= o) ? sc[tid - o] : 0;
        __syncthreads();
        sc[tid] += t;
        __syncthreads();
    }
    int ex = sc[tid] - v;
    int node_g = (cb << CSH) + tid;
    int* rowptr = side ? rowptrD : rowptrS;
    if (node_g < N) rowptr[node_g] = b0 + ex;
    cur[tid] = ex;
    __syncthreads();
    unsigned short* adj = side ? adjD : adjS;
    for (int i = tid; i < tot_rec; i += 256) {
        unsigned int r = rec[b0 + i];
        int node = side ? (int)(r >> 16) : (int)(r & 0xFFFFu);
        unsigned short other = side ? (unsigned short)(r & 0xFFFFu)
                                    : (unsigned short)(r >> 16);
        int p = atomicAdd(&cur[node & 255], 1);
        adj[b0 + p] = other;
    }

    if (side == 0) {
        // fused denom: den[src_local][h] += exp(leaky(al[dst]+ar[src]))
        for (int i = tid; i < tot_rec; i += 256) {
            unsigned int r = rec[b0 + i];
            int src = (int)(r & 0xFFFFu);
            int dst = (int)(r >> 16);
            float4 av = *(const float4*)(al + dst * NH);
            float4 rv = *(const float4*)(ar + src * NH);
            float a0 = av.x + rv.x, a1 = av.y + rv.y;
            float a2 = av.z + rv.z, a3 = av.w + rv.w;
            a0 = (a0 > 0.f) ? a0 : NEG_SLOPE * a0;
            a1 = (a1 > 0.f) ? a1 : NEG_SLOPE * a1;
            a2 = (a2 > 0.f) ? a2 : NEG_SLOPE * a2;
            a3 = (a3 > 0.f) ? a3 : NEG_SLOPE * a3;
            int sl = (src & 255) * NH;
            atomicAdd(&den[sl + 0], __expf(a0));
            atomicAdd(&den[sl + 1], __expf(a1));
            atomicAdd(&den[sl + 2], __expf(a2));
            atomicAdd(&den[sl + 3], __expf(a3));
        }
        __syncthreads();
        if (node_g < N) {
            float4 r4;
            r4.x = 1.0f / (den[tid * NH + 0] + 1e-16f);
            r4.y = 1.0f / (den[tid * NH + 1] + 1e-16f);
            r4.z = 1.0f / (den[tid * NH + 2] + 1e-16f);
            r4.w = 1.0f / (den[tid * NH + 3] + 1e-16f);
            *(float4*)(rdenom + node_g * NH) = r4;
        }
    }
}

// agg over dst-CSR, per-edge weights computed in-wave and shuffled.
// 4 nodes/block (1 node/wave). Chunk 16 edges: lane hh*16+j computes
// w[edge j][head hh]; __shfl broadcasts (s,w); predicated full-unroll
// gather keeps up to 16 h-row loads in flight.
__global__ __launch_bounds__(256) void k_agg(const int* __restrict__ rowptrD,
                                             const unsigned short* __restrict__ adjD,
                                             const float* __restrict__ al,
                                             const float* __restrict__ ar,
                                             const float* __restrict__ rdenom,
                                             const unsigned short* __restrict__ h_bf,
                                             const float* __restrict__ bias,
                                             float* __restrict__ out, int N) {
    int n = blockIdx.x * 4 + (threadIdx.x >> 6);
    if (n >= N) return;
    int lane = threadIdx.x & 63;
    int j    = lane & 15;
    int hh   = lane >> 4;
    int c    = lane * 2;                 // = hh*32 + j*2
    int beg = rowptrD[n], end = rowptrD[n + 1];
    float aln = al[n * NH + hh];
    float a0 = bias[c], a1 = bias[c + 1];
    float b0 = 0.f, b1 = 0.f;
    const int base = lane & 48;          // first lane of this head group

    for (int cb = beg; cb < end; cb += 16) {
        int m = min(16, end - cb);
        int s = 0; float w = 0.f;
        if (j < m) {
            s = adjD[cb + j];
            float a = aln + ar[s * NH + hh];
            a = (a > 0.f) ? a : NEG_SLOPE * a;
            w = __expf(a) * rdenom[s * NH + hh];
        }
        int sk[16]; float wk[16];
#pragma unroll
        for (int k = 0; k < 16; k++) {
            if (k < m) {
                sk[k] = __shfl(s, base + k);
                wk[k] = __shfl(w, base + k);
            } else { sk[k] = 0; wk[k] = 0.f; }
        }
#pragma unroll
        for (int k = 0; k < 16; k += 2) {
            if (k < m) {
                ushort2 u = *(const ushort2*)(h_bf + (size_t)sk[k] * HC + c);
                a0 += bf2f(u.x) * wk[k];
                a1 += bf2f(u.y) * wk[k];
            }
            if (k + 1 < m) {
                ushort2 u = *(const ushort2*)(h_bf + (size_t)sk[k + 1] * HC + c);
                b0 += bf2f(u.x) * wk[k + 1];
                b1 += bf2f(u.y) * wk[k + 1];
            }
        }
    }
    *(float2*)(out + (size_t)n * HC + c) = make_float2(a0 + b0, a1 + b1);
}

extern "C" void kernel_launch(void* const* d_in, const int* in_sizes, int n_in,
                              void* d_out, int out_size, void* d_ws, size_t ws_size,
                              hipStream_t stream) {
    const float* x    = (const float*)d_in[0];
    const float* W    = (const float*)d_in[1];
    const float* att  = (const float*)d_in[2];
    const float* bias = (const float*)d_in[3];
    const int*   ei   = (const int*)d_in[4];

    const int N  = in_sizes[0] / IND;     // 50000
    const int E  = in_sizes[4] / 2;       // 800000
    const int NE = E + N;
    const int ncb = (N + (1 << CSH) - 1) >> CSH;   // 196
    float* out = (float*)d_out;
    const int nodeTot = N * NH;

    // ws layout
    unsigned short* h_bf  = (unsigned short*)d_ws;             // N*128 u16 = 12.8MB
    unsigned short* WT_bf = h_bf + (size_t)N * HC;             // 32K u16
    float* al      = (float*)(WT_bf + IND * HC);               // N*4 f32
    float* ar      = al + nodeTot;                             // N*4
    float* rdenom  = ar + nodeTot;                             // N*4
    unsigned int* recS = (unsigned int*)(rdenom + nodeTot);    // NE u32
    unsigned int* recD = recS + NE;                            // NE u32
    unsigned short* adjS = (unsigned short*)(recD + NE);       // NE u16
    unsigned short* adjD = adjS + NE;                          // NE u16
    int* rowptrS = (int*)(adjD + NE + (NE & 1));               // N+1
    int* rowptrD = rowptrS + (N + 2);                          // N+1
    int* histS   = rowptrD + (N + 2);                          // ncb
    int* histD   = histS + NCB_MAX;                            // ncb
    int* baseS   = histD + NCB_MAX;                            // ncb+1
    int* baseD   = baseS + (NCB_MAX + 1);                      // ncb+1
    int* curS    = baseD + (NCB_MAX + 1);                      // ncb
    int* curD    = curS + NCB_MAX;                             // ncb

    k_prep<<<128, 256, 0, stream>>>(W, WT_bf, histS, histD, ncb);
    k_gemm_mfma<<<(N + 127) / 128, 256, 0, stream>>>(x, WT_bf, att, h_bf, al, ar, N);
    k_hist<<<256, 256, 0, stream>>>(ei, histS, histD, E, NE, ncb);
    k_scanC<<<1, 256, 0, stream>>>(histS, histD, baseS, baseD, curS, curD,
                                   rowptrS, rowptrD, ncb, NE, N);
    k_scatterC<<<(NE + CHUNK - 1) / CHUNK, 256, 0, stream>>>(ei, curS, curD,
                                                             recS, recD, E, NE, ncb);
    k_rebin<<<2 * ncb, 256, 0, stream>>>(recS, recD, baseS, baseD, adjS, adjD,
                                         rowptrS, rowptrD, al, ar, rdenom, ncb, N);
    k_agg<<<(N + 3) / 4, 256, 0, stream>>>(rowptrD, adjD, al, ar, rdenom,
                                           h_bf, bias, out, N);
}